// Round 1
// baseline (1165.344 us; speedup 1.0000x reference)
//
#include <hip/hip_runtime.h>

typedef _Float16 half8 __attribute__((ext_vector_type(8)));
typedef _Float16 half4 __attribute__((ext_vector_type(4)));
typedef float f32x4 __attribute__((ext_vector_type(4)));

#define NTOK 196           // tokens per window (14*14)
#define NPAD 208           // 13 * 16
#define NHEAD 12

__device__ __forceinline__ ushort f2h_u(float f) {
    _Float16 h = (_Float16)f;
    return __builtin_bit_cast(ushort, h);
}

// ---------------- kernel 1: gather x into window-token order, fp32 -> fp16 ----
// out layout: xb[(win*196 + n) * 768 + c], win = ((b*4)+wh)*4+ww, n = r*14+cc
__global__ __launch_bounds__(256) void cvt_x(const float* __restrict__ x,
                                             ushort* __restrict__ xb) {
    int idx = blockIdx.x * 256 + threadIdx.x;        // < 50176*192 exactly
    int t   = idx / 192;
    int c   = (idx - t * 192) * 4;
    int win = t / NTOK;
    int n   = t - win * NTOK;
    int b  = win >> 4, wh = (win >> 2) & 3, ww = win & 3;
    int r  = n / 14,  cc = n - r * 14;
    const float4 v = *(const float4*)(x + (((b * 56 + wh * 14 + r) * 56) + ww * 14 + cc) * 768 + c);
    ushort4 o = make_ushort4(f2h_u(v.x), f2h_u(v.y), f2h_u(v.z), f2h_u(v.w));
    *(ushort4*)(xb + t * 768 + c) = o;
}

// ---------------- kernel 2: weights fp32 -> fp16 -----------------------------
__global__ __launch_bounds__(256) void cvt_w(const float* __restrict__ qkv_w,
                                             const float* __restrict__ proj_w,
                                             ushort* __restrict__ wq,
                                             ushort* __restrict__ wp) {
    int idx = blockIdx.x * 256 + threadIdx.x;        // < 3072*192 exactly
    int row = idx / 192;
    int c   = (idx - row * 192) * 4;
    const float* src;
    ushort* dst;
    if (row < 2304) { src = qkv_w + row * 768 + c;          dst = wq + row * 768 + c; }
    else            { src = proj_w + (row - 2304) * 768 + c; dst = wp + (row - 2304) * 768 + c; }
    float4 v = *(const float4*)src;
    *(ushort4*)dst = make_ushort4(f2h_u(v.x), f2h_u(v.y), f2h_u(v.z), f2h_u(v.w));
}

// ---------------- kernel 3: fused QKV GEMM + attention, one block per (win,head)
// 8 waves (512 thr). Phase1: 224x192 GEMM K=768 (wave-tile 112x48, N-tiles {wn,4+wn,8+wn}).
// q,k -> LDS (f16), v -> regs. Phase2: S=QK^T per 16-row strip, exact softmax in regs,
// P via wave-private LDS scratch (C->A layout), O = P V.  LDS total 53,248 B.
__global__ __launch_bounds__(512) void qkv_attn(const ushort* __restrict__ xb,
                                                const ushort* __restrict__ wq,
                                                const float* __restrict__ qkv_b,
                                                ushort* __restrict__ o_ws) {
    __shared__ __align__(16) ushort R1[13312];  // x_tile[224][32]+w_tile[192][32] -> q_s[208][64] -> pscr
    __shared__ __align__(16) ushort R2[13312];  // k_s[208][64] -> v_t[64][208]

    const int tid  = threadIdx.x;
    const int wave = tid >> 6, lane = tid & 63;
    const int quad = lane >> 4, l16 = lane & 15;
    const int wm = wave >> 2, wn = wave & 3;           // wave grid 2(M) x 4(N)
    const int win  = blockIdx.x / NHEAD;
    const int head = blockIdx.x - win * NHEAD;

    ushort* x_tile = R1;           // [224][32]
    ushort* w_tile = R1 + 7168;    // [192][32]

    f32x4 acc[7][3];
    #pragma unroll
    for (int i = 0; i < 7; ++i)
        #pragma unroll
        for (int j = 0; j < 3; ++j)
            acc[i][j] = (f32x4){0.f, 0.f, 0.f, 0.f};

    const ushort* xw = xb + win * NTOK * 768;

    // ---- phase 1: qkv = xw @ Wqkv^T ----
    for (int kt = 0; kt < 24; ++kt) {
        const int k0 = kt * 32;
        for (int ch = tid; ch < 1792; ch += 512) {      // x_tile: 224*32/4 chunks
            int row = ch >> 3, col = (ch & 7) << 2;
            uint2 val = make_uint2(0u, 0u);
            if (row < NTOK) val = *(const uint2*)(xw + row * 768 + k0 + col);
            *(uint2*)(x_tile + row * 32 + col) = val;
        }
        for (int ch = tid; ch < 1536; ch += 512) {      // w_tile: 192*32/4 chunks
            int n = ch >> 3, col = (ch & 7) << 2;
            int wrow = ((n >> 6) * 768) + head * 64 + (n & 63);
            *(uint2*)(w_tile + n * 32 + col) = *(const uint2*)(wq + wrow * 768 + k0 + col);
        }
        __syncthreads();
        half8 b0 = *(const half8*)(w_tile + ((wn)     * 16 + l16) * 32 + quad * 8);
        half8 b1 = *(const half8*)(w_tile + ((4 + wn) * 16 + l16) * 32 + quad * 8);
        half8 b2 = *(const half8*)(w_tile + ((8 + wn) * 16 + l16) * 32 + quad * 8);
        #pragma unroll
        for (int mi = 0; mi < 7; ++mi) {
            half8 a = *(const half8*)(x_tile + (wm * 112 + mi * 16 + l16) * 32 + quad * 8);
            acc[mi][0] = __builtin_amdgcn_mfma_f32_16x16x32_f16(a, b0, acc[mi][0], 0, 0, 0);
            acc[mi][1] = __builtin_amdgcn_mfma_f32_16x16x32_f16(a, b1, acc[mi][1], 0, 0, 0);
            acc[mi][2] = __builtin_amdgcn_mfma_f32_16x16x32_f16(a, b2, acc[mi][2], 0, 0, 0);
        }
        __syncthreads();
    }

    // ---- phase 1 epilogue: +bias; q->R1, k->R2 (f16), v held in regs ----
    const int dloc = wn * 16 + l16;                     // 0..63 within head
    const float bq = qkv_b[head * 64 + dloc];
    const float bk = qkv_b[768 + head * 64 + dloc];
    const float bv = qkv_b[1536 + head * 64 + dloc];
    f32x4 vhold[7];
    #pragma unroll
    for (int mi = 0; mi < 7; ++mi) {
        #pragma unroll
        for (int r = 0; r < 4; ++r) {
            int token = wm * 112 + mi * 16 + quad * 4 + r;
            if (token < NPAD) {
                R1[token * 64 + dloc] = f2h_u(acc[mi][0][r] + bq);   // q_s[token][d]
                R2[token * 64 + dloc] = f2h_u(acc[mi][1][r] + bk);   // k_s[token][d]
            }
            vhold[mi][r] = acc[mi][2][r] + bv;
        }
    }
    __syncthreads();

    // ---- phase 2a: S = q k^T * scale + exact softmax (per 16-row strip) ----
    const int nstrip = (wave < 5) ? 2 : 1;              // 13 strips over 8 waves
    float P[2][13][4];                                  // exp(s - m), unnormalized
    float lsum[2][4];
    #pragma unroll
    for (int si = 0; si < 2; ++si) {
        if (si < nstrip) {
            const int sb = (si == 0 ? wave : wave + 8) * 16;
            half8 aq0 = *(const half8*)(R1 + (sb + l16) * 64 + quad * 8);
            half8 aq1 = *(const half8*)(R1 + (sb + l16) * 64 + 32 + quad * 8);
            f32x4 sacc[13];
            #pragma unroll
            for (int nt = 0; nt < 13; ++nt) sacc[nt] = (f32x4){0.f, 0.f, 0.f, 0.f};
            #pragma unroll
            for (int nt = 0; nt < 13; ++nt) {
                half8 kb0 = *(const half8*)(R2 + (nt * 16 + l16) * 64 + quad * 8);
                half8 kb1 = *(const half8*)(R2 + (nt * 16 + l16) * 64 + 32 + quad * 8);
                sacc[nt] = __builtin_amdgcn_mfma_f32_16x16x32_f16(aq0, kb0, sacc[nt], 0, 0, 0);
                sacc[nt] = __builtin_amdgcn_mfma_f32_16x16x32_f16(aq1, kb1, sacc[nt], 0, 0, 0);
            }
            #pragma unroll
            for (int r = 0; r < 4; ++r) {
                float sv[13];
                float mx = -1e30f;
                #pragma unroll
                for (int nt = 0; nt < 13; ++nt) {
                    float s = sacc[nt][r] * 0.125f;
                    if (nt == 12 && l16 >= 4) s = -1e30f;   // mask cols >= 196
                    sv[nt] = s;
                    mx = fmaxf(mx, s);
                }
                mx = fmaxf(mx, __shfl_xor(mx, 1));
                mx = fmaxf(mx, __shfl_xor(mx, 2));
                mx = fmaxf(mx, __shfl_xor(mx, 4));
                mx = fmaxf(mx, __shfl_xor(mx, 8));
                float l = 0.f;
                #pragma unroll
                for (int nt = 0; nt < 13; ++nt) {
                    float e = __expf(sv[nt] - mx);
                    P[si][nt][r] = e;
                    l += e;
                }
                l += __shfl_xor(l, 1);
                l += __shfl_xor(l, 2);
                l += __shfl_xor(l, 4);
                l += __shfl_xor(l, 8);
                lsum[si][r] = l;
            }
        }
    }
    __syncthreads();                                    // q_s, k_s now dead

    // ---- write v_t[64][208] (overwrites k_s region) ----
    #pragma unroll
    for (int mi = 0; mi < 7; ++mi) {
        #pragma unroll
        for (int r = 0; r < 4; ++r) {
            int token = wm * 112 + mi * 16 + quad * 4 + r;
            if (token < NPAD) R2[dloc * NPAD + token] = f2h_u(vhold[mi][r]);
        }
    }
    __syncthreads();

    // ---- phase 2c: O = P V ----
    ushort* pscr = R1 + wave * 512;                     // 16 x 32 f16, wave-private
    #pragma unroll
    for (int si = 0; si < 2; ++si) {
        if (si < nstrip) {
            f32x4 oacc[4];
            #pragma unroll
            for (int dt = 0; dt < 4; ++dt) oacc[dt] = (f32x4){0.f, 0.f, 0.f, 0.f};
            #pragma unroll
            for (int ks = 0; ks < 6; ++ks) {            // K = 32 steps, tokens 0..191
                #pragma unroll
                for (int h = 0; h < 2; ++h) {
                    int nt = ks * 2 + h;
                    #pragma unroll
                    for (int r = 0; r < 4; ++r)
                        pscr[(quad * 4 + r) * 32 + h * 16 + l16] = f2h_u(P[si][nt][r]);
                }
                half8 a = *(const half8*)(pscr + l16 * 32 + quad * 8);
                #pragma unroll
                for (int dt = 0; dt < 4; ++dt) {
                    half8 vb = *(const half8*)(R2 + (dt * 16 + l16) * NPAD + ks * 32 + quad * 8);
                    oacc[dt] = __builtin_amdgcn_mfma_f32_16x16x32_f16(a, vb, oacc[dt], 0, 0, 0);
                }
            }
            {                                           // final K = 16 step, tokens 192..207
                #pragma unroll
                for (int r = 0; r < 4; ++r)
                    pscr[(quad * 4 + r) * 32 + l16] = f2h_u(P[si][12][r]);
                half4 a4 = *(const half4*)(pscr + l16 * 32 + quad * 4);
                #pragma unroll
                for (int dt = 0; dt < 4; ++dt) {
                    half4 vb4 = *(const half4*)(R2 + (dt * 16 + l16) * NPAD + 192 + quad * 4);
                    oacc[dt] = __builtin_amdgcn_mfma_f32_16x16x16f16(a4, vb4, oacc[dt], 0, 0, 0);
                }
            }
            const int sb = (si == 0 ? wave : wave + 8) * 16;
            #pragma unroll
            for (int r = 0; r < 4; ++r) {
                int token = sb + quad * 4 + r;
                if (token < NTOK) {
                    float inv = 1.f / lsum[si][r];
                    #pragma unroll
                    for (int dt = 0; dt < 4; ++dt)
                        o_ws[(win * NTOK + token) * 768 + head * 64 + dt * 16 + l16] =
                            f2h_u(oacc[dt][r] * inv);
                }
            }
        }
    }
}

// ---------------- kernel 4: proj GEMM (50176x768x768) + window scatter -------
__global__ __launch_bounds__(256) void proj_k(const ushort* __restrict__ ow,
                                              const ushort* __restrict__ wp,
                                              const float* __restrict__ pb,
                                              float* __restrict__ out) {
    __shared__ __align__(16) ushort a_s[128 * 32];
    __shared__ __align__(16) ushort b_s[128 * 32];
    const int tid = threadIdx.x, wave = tid >> 6, lane = tid & 63;
    const int quad = lane >> 4, l16 = lane & 15;
    const int mblk = blockIdx.x / 6, nblk = blockIdx.x - mblk * 6;
    const int wmo = (wave >> 1) * 64, wno = (wave & 1) * 64;

    f32x4 acc[4][4];
    #pragma unroll
    for (int i = 0; i < 4; ++i)
        #pragma unroll
        for (int j = 0; j < 4; ++j) acc[i][j] = (f32x4){0.f, 0.f, 0.f, 0.f};

    for (int kt = 0; kt < 24; ++kt) {
        const int k0 = kt * 32;
        for (int ch = tid; ch < 1024; ch += 256) {
            int row = ch >> 3, col = (ch & 7) << 2;
            *(uint2*)(a_s + row * 32 + col) = *(const uint2*)(ow + (mblk * 128 + row) * 768 + k0 + col);
            *(uint2*)(b_s + row * 32 + col) = *(const uint2*)(wp + (nblk * 128 + row) * 768 + k0 + col);
        }
        __syncthreads();
        half8 bf[4];
        #pragma unroll
        for (int ni = 0; ni < 4; ++ni)
            bf[ni] = *(const half8*)(b_s + (wno + ni * 16 + l16) * 32 + quad * 8);
        #pragma unroll
        for (int mi = 0; mi < 4; ++mi) {
            half8 a = *(const half8*)(a_s + (wmo + mi * 16 + l16) * 32 + quad * 8);
            #pragma unroll
            for (int ni = 0; ni < 4; ++ni)
                acc[mi][ni] = __builtin_amdgcn_mfma_f32_16x16x32_f16(a, bf[ni], acc[mi][ni], 0, 0, 0);
        }
        __syncthreads();
    }
    #pragma unroll
    for (int mi = 0; mi < 4; ++mi) {
        #pragma unroll
        for (int r = 0; r < 4; ++r) {
            int grow = mblk * 128 + wmo + mi * 16 + quad * 4 + r;   // < 50176
            int wnd = grow / 196, tok = grow - wnd * 196;
            int b = wnd >> 4, wh = (wnd >> 2) & 3, ww = wnd & 3;
            int rr = tok / 14, cc = tok - rr * 14;
            float* orow = out + ((b * 56 + wh * 14 + rr) * 56 + ww * 14 + cc) * 768;
            #pragma unroll
            for (int ni = 0; ni < 4; ++ni) {
                int col = nblk * 128 + wno + ni * 16 + l16;
                orow[col] = acc[mi][ni][r] + pb[col];
            }
        }
    }
}

extern "C" void kernel_launch(void* const* d_in, const int* in_sizes, int n_in,
                              void* d_out, int out_size, void* d_ws, size_t ws_size,
                              hipStream_t stream) {
    const float* x      = (const float*)d_in[0];
    const float* qkv_w  = (const float*)d_in[1];
    const float* qkv_b  = (const float*)d_in[2];
    const float* proj_w = (const float*)d_in[3];
    const float* proj_b = (const float*)d_in[4];
    float* out = (float*)d_out;

    char* ws = (char*)d_ws;
    ushort* xb = (ushort*)(ws);                       // 50176*768 f16 = 77,070,336 B
    ushort* ow = (ushort*)(ws + 77070336);            // 50176*768 f16
    ushort* wq = (ushort*)(ws + 154140672);           // 2304*768 f16 = 3,538,944 B
    ushort* wp = (ushort*)(ws + 157679616);           // 768*768 f16  = 1,179,648 B
    // total workspace: 158,859,264 B

    cvt_x<<<37632, 256, 0, stream>>>(x, xb);          // 37632*256 == 50176*192
    cvt_w<<<2304, 256, 0, stream>>>(qkv_w, proj_w, wq, wp);
    qkv_attn<<<256 * NHEAD, 512, 0, stream>>>(xb, wq, qkv_b, ow);
    proj_k<<<392 * 6, 256, 0, stream>>>(ow, wp, proj_b, out);
}

// Round 2
// 909.274 us; speedup vs baseline: 1.2816x; 1.2816x over previous
//
#include <hip/hip_runtime.h>

typedef _Float16 half8 __attribute__((ext_vector_type(8)));
typedef _Float16 half4 __attribute__((ext_vector_type(4)));
typedef float f32x4 __attribute__((ext_vector_type(4)));

#define NTOK 196           // tokens per window (14*14)
#define NHEAD 12

__device__ __forceinline__ ushort f2h_u(float f) {
    _Float16 h = (_Float16)f;
    return __builtin_bit_cast(ushort, h);
}

// async 16B global->LDS. lds ptr must be wave-uniform base; HW adds lane*16.
__device__ __forceinline__ void gl_lds16(const ushort* g, ushort* l) {
    __builtin_amdgcn_global_load_lds((const __attribute__((address_space(1))) void*)g,
                                     (__attribute__((address_space(3))) void*)l,
                                     16, 0, 0);
}

// ---------------- kernel 1: gather x into window-token order, fp32 -> fp16 ----
__global__ __launch_bounds__(256) void cvt_x(const float* __restrict__ x,
                                             ushort* __restrict__ xb) {
    int idx = blockIdx.x * 256 + threadIdx.x;        // < 50176*192 exactly
    int t   = idx / 192;
    int c   = (idx - t * 192) * 4;
    int win = t / NTOK;
    int n   = t - win * NTOK;
    int b  = win >> 4, wh = (win >> 2) & 3, ww = win & 3;
    int r  = n / 14,  cc = n - r * 14;
    const float4 v = *(const float4*)(x + (((b * 56 + wh * 14 + r) * 56) + ww * 14 + cc) * 768 + c);
    ushort4 o = make_ushort4(f2h_u(v.x), f2h_u(v.y), f2h_u(v.z), f2h_u(v.w));
    *(ushort4*)(xb + t * 768 + c) = o;
}

// ---------------- kernel 2: weights fp32 -> fp16 -----------------------------
__global__ __launch_bounds__(256) void cvt_w(const float* __restrict__ qkv_w,
                                             const float* __restrict__ proj_w,
                                             ushort* __restrict__ wq,
                                             ushort* __restrict__ wp) {
    int idx = blockIdx.x * 256 + threadIdx.x;        // < 3072*192 exactly
    int row = idx / 192;
    int c   = (idx - row * 192) * 4;
    const float* src;
    ushort* dst;
    if (row < 2304) { src = qkv_w + row * 768 + c;          dst = wq + row * 768 + c; }
    else            { src = proj_w + (row - 2304) * 768 + c; dst = wp + (row - 2304) * 768 + c; }
    float4 v = *(const float4*)src;
    *(ushort4*)dst = make_ushort4(f2h_u(v.x), f2h_u(v.y), f2h_u(v.z), f2h_u(v.w));
}

// ---------------- kernel 3: QKV GEMM (m97 structure, 128x128, BK=32) ---------
// C[m, col] over Mc x 2304, K=768. sec = nblk/6 (0=q,1=k,2=v), per-block uniform.
// q,k -> [m][768] f16 natural; v -> vt[head][win][64][208] f16 transposed.
__global__ __launch_bounds__(256) void gemm_qkv(const ushort* __restrict__ A,
                                                const ushort* __restrict__ Wq,
                                                const float* __restrict__ qkv_b,
                                                ushort* __restrict__ qbuf,
                                                ushort* __restrict__ kbuf,
                                                ushort* __restrict__ vt,
                                                int MB, int Wc) {
    __shared__ __align__(16) ushort a_s[128 * 32];   // 8 KB
    __shared__ __align__(16) ushort b_s[128 * 32];   // 8 KB
    const int tid = threadIdx.x, wave = tid >> 6, lane = tid & 63;
    const int quad = lane >> 4, l16 = lane & 15;
    const int mblk = blockIdx.x % MB, nblk = blockIdx.x / MB;
    const int wmo = (wave >> 1) * 64, wno = (wave & 1) * 64;

    f32x4 acc[4][4];
    #pragma unroll
    for (int i = 0; i < 4; ++i)
        #pragma unroll
        for (int j = 0; j < 4; ++j) acc[i][j] = (f32x4){0.f, 0.f, 0.f, 0.f};

    const ushort* Ab = A  + (size_t)mblk * 128 * 768;
    const ushort* Bb = Wq + (size_t)nblk * 128 * 768;

    for (int kt = 0; kt < 24; ++kt) {
        const int k0 = kt * 32;
        #pragma unroll
        for (int p = 0; p < 2; ++p) {
            const int u0 = (p * 4 + wave) * 64;      // wave-uniform chunk base
            const int t  = u0 + lane;
            const int row = t >> 2, c8 = t & 3;      // 4x16B chunks per 32-f16 row
            gl_lds16(Ab + row * 768 + k0 + c8 * 8, a_s + u0 * 8);
            gl_lds16(Bb + row * 768 + k0 + c8 * 8, b_s + u0 * 8);
        }
        __syncthreads();
        half8 bf[4];
        #pragma unroll
        for (int ni = 0; ni < 4; ++ni)
            bf[ni] = *(const half8*)(b_s + (wno + ni * 16 + l16) * 32 + quad * 8);
        #pragma unroll
        for (int mi = 0; mi < 4; ++mi) {
            half8 a = *(const half8*)(a_s + (wmo + mi * 16 + l16) * 32 + quad * 8);
            #pragma unroll
            for (int ni = 0; ni < 4; ++ni)
                acc[mi][ni] = __builtin_amdgcn_mfma_f32_16x16x32_f16(a, bf[ni], acc[mi][ni], 0, 0, 0);
        }
        __syncthreads();
    }

    const int sec = nblk / 6;                         // block-uniform
    const int cbase = (nblk - sec * 6) * 128 + wno;
    #pragma unroll
    for (int ni = 0; ni < 4; ++ni) {
        const int col_in = cbase + ni * 16 + l16;     // 0..767
        const float bias = qkv_b[sec * 768 + col_in];
        #pragma unroll
        for (int mi = 0; mi < 4; ++mi) {
            #pragma unroll
            for (int r = 0; r < 4; ++r) {
                const int m = mblk * 128 + wmo + mi * 16 + quad * 4 + r;
                const float v = acc[mi][ni][r] + bias;
                if (sec == 0) {
                    qbuf[(size_t)m * 768 + col_in] = f2h_u(v);
                } else if (sec == 1) {
                    kbuf[(size_t)m * 768 + col_in] = f2h_u(v);
                } else {
                    const int win = m / 196, tok = m - win * 196;
                    const int head = col_in >> 6, d = col_in & 63;
                    vt[((size_t)(head * Wc + win) * 64 + d) * 208 + tok] = f2h_u(v);
                }
            }
        }
    }
}

// ---------------- kernel 4: attention per (win, head), 4 waves ---------------
// k_s: two stride-32 halves (even bank spread); v_t padded to 216 (even spread).
__global__ __launch_bounds__(256) void attn(const ushort* __restrict__ qbuf,
                                            const ushort* __restrict__ kbuf,
                                            const ushort* __restrict__ vt,
                                            ushort* __restrict__ ow, int Wc) {
    __shared__ __align__(16) ushort k_s[2 * 208 * 32];   // 26,624 B
    __shared__ __align__(16) ushort v_t[64 * 216];       // 27,648 B
    __shared__ __align__(16) ushort pscr[4 * 512];       //  4,096 B
    const int tid = threadIdx.x, wave = tid >> 6, lane = tid & 63;
    const int quad = lane >> 4, l16 = lane & 15;
    const int head = blockIdx.x % NHEAD, win = blockIdx.x / NHEAD;

    // early q fragment loads (in flight behind staging + barrier)
    half8 aq0[4], aq1[4];
    #pragma unroll
    for (int si = 0; si < 4; ++si) {
        int strip = wave + si * 4; if (strip > 12) strip = 12;
        int qtok = strip * 16 + l16; if (qtok > 195) qtok = 195;
        const ushort* qp = qbuf + (size_t)(win * NTOK + qtok) * 768 + head * 64 + quad * 8;
        aq0[si] = *(const half8*)qp;
        aq1[si] = *(const half8*)(qp + 32);
    }

    // stage k (zero-pad rows >=196), split halves d<32 / d>=32
    for (int c = tid; c < 1664; c += 256) {
        const int row = c >> 3, c8 = c & 7;
        half8 val = {};
        if (row < NTOK)
            val = *(const half8*)(kbuf + (size_t)(win * NTOK + row) * 768 + head * 64 + c8 * 8);
        *(half8*)(k_s + ((c8 >> 2) * 208 + row) * 32 + (c8 & 3) * 8) = val;
    }
    // stage v_t (global vt already transposed; pad cols 196..207 are zeroed via memset)
    {
        const ushort* vsrc = vt + (size_t)(head * Wc + win) * 64 * 208;
        for (int c = tid; c < 1664; c += 256) {
            const int d = c / 26, c8 = c - d * 26;
            *(half8*)(v_t + d * 216 + c8 * 8) = *(const half8*)(vsrc + d * 208 + c8 * 8);
        }
    }
    __syncthreads();

    ushort* ps = pscr + wave * 512;
    for (int si = 0; si < 4; ++si) {
        const int strip = wave + si * 4;
        if (strip > 12) break;                        // wave-uniform
        // ---- S = q k^T ----
        f32x4 sacc[13];
        #pragma unroll
        for (int nt = 0; nt < 13; ++nt) sacc[nt] = (f32x4){0.f, 0.f, 0.f, 0.f};
        #pragma unroll
        for (int nt = 0; nt < 13; ++nt) {
            const int krow = (nt * 16 + l16) * 32 + quad * 8;
            half8 kb0 = *(const half8*)(k_s + krow);
            half8 kb1 = *(const half8*)(k_s + 208 * 32 + krow);
            sacc[nt] = __builtin_amdgcn_mfma_f32_16x16x32_f16(aq0[si], kb0, sacc[nt], 0, 0, 0);
            sacc[nt] = __builtin_amdgcn_mfma_f32_16x16x32_f16(aq1[si], kb1, sacc[nt], 0, 0, 0);
        }
        // ---- exact softmax per row (cols spread over l16) ----
        float P[13][4], linv[4];
        #pragma unroll
        for (int r = 0; r < 4; ++r) {
            float sv[13];
            float mx = -1e30f;
            #pragma unroll
            for (int nt = 0; nt < 13; ++nt) {
                float s = sacc[nt][r] * 0.125f;
                if (nt == 12 && l16 >= 4) s = -1e30f;   // mask cols >= 196
                sv[nt] = s;
                mx = fmaxf(mx, s);
            }
            mx = fmaxf(mx, __shfl_xor(mx, 1));
            mx = fmaxf(mx, __shfl_xor(mx, 2));
            mx = fmaxf(mx, __shfl_xor(mx, 4));
            mx = fmaxf(mx, __shfl_xor(mx, 8));
            float l = 0.f;
            #pragma unroll
            for (int nt = 0; nt < 13; ++nt) {
                float e = __expf(sv[nt] - mx);
                P[nt][r] = e;
                l += e;
            }
            l += __shfl_xor(l, 1);
            l += __shfl_xor(l, 2);
            l += __shfl_xor(l, 4);
            l += __shfl_xor(l, 8);
            linv[r] = 1.f / l;
        }
        // ---- O = P V ----
        f32x4 oacc[4];
        #pragma unroll
        for (int dt = 0; dt < 4; ++dt) oacc[dt] = (f32x4){0.f, 0.f, 0.f, 0.f};
        #pragma unroll
        for (int ks = 0; ks < 6; ++ks) {              // K=32 steps, tokens 0..191
            #pragma unroll
            for (int h = 0; h < 2; ++h) {
                const int nt = ks * 2 + h;
                #pragma unroll
                for (int r = 0; r < 4; ++r)
                    ps[(quad * 4 + r) * 32 + h * 16 + l16] = f2h_u(P[nt][r]);
            }
            half8 a = *(const half8*)(ps + l16 * 32 + quad * 8);
            #pragma unroll
            for (int dt = 0; dt < 4; ++dt) {
                half8 vb = *(const half8*)(v_t + (dt * 16 + l16) * 216 + ks * 32 + quad * 8);
                oacc[dt] = __builtin_amdgcn_mfma_f32_16x16x32_f16(a, vb, oacc[dt], 0, 0, 0);
            }
        }
        {                                             // final K=16, tokens 192..207
            #pragma unroll
            for (int r = 0; r < 4; ++r)
                ps[(quad * 4 + r) * 32 + l16] = f2h_u(P[12][r]);
            half4 a4 = *(const half4*)(ps + l16 * 32 + quad * 4);
            #pragma unroll
            for (int dt = 0; dt < 4; ++dt) {
                half4 vb4 = *(const half4*)(v_t + (dt * 16 + l16) * 216 + 192 + quad * 4);
                oacc[dt] = __builtin_amdgcn_mfma_f32_16x16x16f16(a4, vb4, oacc[dt], 0, 0, 0);
            }
        }
        // ---- store ----
        const int sb = strip * 16;
        #pragma unroll
        for (int r = 0; r < 4; ++r) {
            const int token = sb + quad * 4 + r;
            if (token < NTOK) {
                #pragma unroll
                for (int dt = 0; dt < 4; ++dt)
                    ow[(size_t)(win * NTOK + token) * 768 + head * 64 + dt * 16 + l16] =
                        f2h_u(oacc[dt][r] * linv[r]);
            }
        }
    }
}

// ---------------- kernel 5: proj GEMM (50176x768x768) + window scatter -------
__global__ __launch_bounds__(256) void proj_k(const ushort* __restrict__ ow,
                                              const ushort* __restrict__ wp,
                                              const float* __restrict__ pb,
                                              float* __restrict__ out) {
    __shared__ __align__(16) ushort a_s[128 * 32];
    __shared__ __align__(16) ushort b_s[128 * 32];
    const int tid = threadIdx.x, wave = tid >> 6, lane = tid & 63;
    const int quad = lane >> 4, l16 = lane & 15;
    const int mblk = blockIdx.x / 6, nblk = blockIdx.x - mblk * 6;
    const int wmo = (wave >> 1) * 64, wno = (wave & 1) * 64;

    f32x4 acc[4][4];
    #pragma unroll
    for (int i = 0; i < 4; ++i)
        #pragma unroll
        for (int j = 0; j < 4; ++j) acc[i][j] = (f32x4){0.f, 0.f, 0.f, 0.f};

    for (int kt = 0; kt < 24; ++kt) {
        const int k0 = kt * 32;
        #pragma unroll
        for (int p = 0; p < 2; ++p) {
            const int u0 = (p * 4 + wave) * 64;
            const int t  = u0 + lane;
            const int row = t >> 2, c8 = t & 3;
            gl_lds16(ow + (size_t)(mblk * 128 + row) * 768 + k0 + c8 * 8, a_s + u0 * 8);
            gl_lds16(wp + (size_t)(nblk * 128 + row) * 768 + k0 + c8 * 8, b_s + u0 * 8);
        }
        __syncthreads();
        half8 bf[4];
        #pragma unroll
        for (int ni = 0; ni < 4; ++ni)
            bf[ni] = *(const half8*)(b_s + (wno + ni * 16 + l16) * 32 + quad * 8);
        #pragma unroll
        for (int mi = 0; mi < 4; ++mi) {
            half8 a = *(const half8*)(a_s + (wmo + mi * 16 + l16) * 32 + quad * 8);
            #pragma unroll
            for (int ni = 0; ni < 4; ++ni)
                acc[mi][ni] = __builtin_amdgcn_mfma_f32_16x16x32_f16(a, bf[ni], acc[mi][ni], 0, 0, 0);
        }
        __syncthreads();
    }
    #pragma unroll
    for (int mi = 0; mi < 4; ++mi) {
        #pragma unroll
        for (int r = 0; r < 4; ++r) {
            int grow = mblk * 128 + wmo + mi * 16 + quad * 4 + r;   // < 50176
            int wnd = grow / 196, tok = grow - wnd * 196;
            int b = wnd >> 4, wh = (wnd >> 2) & 3, ww = wnd & 3;
            int rr = tok / 14, cc = tok - rr * 14;
            float* orow = out + ((b * 56 + wh * 14 + rr) * 56 + ww * 14 + cc) * 768;
            #pragma unroll
            for (int ni = 0; ni < 4; ++ni) {
                int col = nblk * 128 + wno + ni * 16 + l16;
                orow[col] = acc[mi][ni][r] + pb[col];
            }
        }
    }
}

extern "C" void kernel_launch(void* const* d_in, const int* in_sizes, int n_in,
                              void* d_out, int out_size, void* d_ws, size_t ws_size,
                              hipStream_t stream) {
    const float* x      = (const float*)d_in[0];
    const float* qkv_w  = (const float*)d_in[1];
    const float* qkv_b  = (const float*)d_in[2];
    const float* proj_w = (const float*)d_in[3];
    const float* proj_b = (const float*)d_in[4];
    float* out = (float*)d_out;

    char* ws = (char*)d_ws;
    ushort* xb = (ushort*)ws;                         // 77,070,336 B; later aliased as ow
    ushort* wq = (ushort*)(ws + 77070336);            //  3,538,944 B
    ushort* wp = (ushort*)(ws + 80609280);            //  1,179,648 B
    char* dyn = ws + 81788928;

    // chunk window count by available workspace (q + k + vt per window = 921,600 B)
    size_t avail = ws_size > 81788928u ? ws_size - 81788928u : 0;
    int Wc = 256;
    while (Wc > 32 && (size_t)Wc * 921600u > avail) Wc >>= 1;
    const int nchunk = 256 / Wc;
    const int MB = Wc * NTOK / 128;                   // Wc multiple of 32 -> exact

    ushort* qbuf = (ushort*)dyn;
    ushort* kbuf = qbuf + (size_t)Wc * NTOK * 768;
    ushort* vt   = kbuf + (size_t)Wc * NTOK * 768;

    cvt_x<<<37632, 256, 0, stream>>>(x, xb);
    cvt_w<<<2304, 256, 0, stream>>>(qkv_w, proj_w, wq, wp);
    hipMemsetAsync(vt, 0, (size_t)Wc * NHEAD * 64 * 208 * 2, stream);  // zero vt pad cols

    for (int c = 0; c < nchunk; ++c) {
        const ushort* xbc = xb + (size_t)c * Wc * NTOK * 768;
        ushort* owc = xb + (size_t)c * Wc * NTOK * 768;   // alias: chunk's xb dead after gemm
        gemm_qkv<<<MB * 18, 256, 0, stream>>>(xbc, wq, qkv_b, qbuf, kbuf, vt, MB, Wc);
        attn<<<Wc * NHEAD, 256, 0, stream>>>(qbuf, kbuf, vt, owc, Wc);
    }
    proj_k<<<392 * 6, 256, 0, stream>>>(xb, wp, proj_b, out);
}